// Round 8
// baseline (546.473 us; speedup 1.0000x reference)
//
#include <hip/hip_runtime.h>
#include <hip/hip_bf16.h>
#include <math.h>

// ---------------- problem constants ----------------
#define M 8192
#define N 16384
#define D 64
#define ZC 58.81206612509905f        // 32*log(2*pi), h=1
#define B0 24.0f                     // exp2-domain bias (headroom; u<=0)
#define LOG2E 1.4426950408889634f
#define HL2E 0.7213475204444817f     // 0.5*log2(e)
#define LN2 0.6931471805599453f

// Schraudolph exp2: 2^u ~= bitcast(int(u*2^23 + (127 - 0.0435)*2^23)).
// Bias-corrected midpoint => max rel err ~±3% (log-output err <= 0.04,
// same order as existing bf16 dot noise; tolerance 0.5).
#define SCH_K 8388608.0f             // 2^23
#define SCH_C (1065353216.0f - 0.0435f * 8388608.0f)

#define PCH 32
#define NCHK (N / PCH)               // 512 train cols per block

typedef short v8bf __attribute__((ext_vector_type(8)));   // 8 bf16 (4 VGPRs)
typedef float v16f __attribute__((ext_vector_type(16)));

// ws layout (bytes)
#define B_AU2  0                        // 8192 f32  (32 KB)
#define B_LW2  32768                    // 16384 f32 (64 KB)
#define B_PART 98304                    // 32*8192 f32 (1 MB), [chunk][m]
#define B_TB   1146880                  // 8192*64 bf16 (1 MB)
#define B_TR   2195456                  // 16384*64 bf16 (2 MB)

// Fused prep: blocks 0..255 convert testX -> bf16(log2e*x) + au2;
// blocks 256..767 convert trainX -> bf16 + lw2 = log2(w) - hl2e*r2 + B0.
__global__ __launch_bounds__(256) void gk_prep(const float* __restrict__ testX,
                                               const float* __restrict__ trainX,
                                               const float* __restrict__ sw,
                                               __hip_bfloat16* __restrict__ tb,
                                               __hip_bfloat16* __restrict__ rb,
                                               float* __restrict__ au2,
                                               float* __restrict__ lw2) {
    const int tid = threadIdx.x;
    const int e = tid & 7;
    if (blockIdx.x < M / 32) {
        const int row = blockIdx.x * 32 + (tid >> 3);
        const float4* p = reinterpret_cast<const float4*>(testX + (size_t)row * D + e * 8);
        float4 v0 = p[0], v1 = p[1];
        float t2 = v0.x * v0.x + v0.y * v0.y + v0.z * v0.z + v0.w * v0.w
                 + v1.x * v1.x + v1.y * v1.y + v1.z * v1.z + v1.w * v1.w;
        t2 += __shfl_xor(t2, 1, 64);
        t2 += __shfl_xor(t2, 2, 64);
        t2 += __shfl_xor(t2, 4, 64);
        if (e == 0) au2[row] = -HL2E * t2;
        union { __hip_bfloat16 h[8]; uint4 u; } cv;
        cv.h[0] = __float2bfloat16(v0.x * LOG2E);
        cv.h[1] = __float2bfloat16(v0.y * LOG2E);
        cv.h[2] = __float2bfloat16(v0.z * LOG2E);
        cv.h[3] = __float2bfloat16(v0.w * LOG2E);
        cv.h[4] = __float2bfloat16(v1.x * LOG2E);
        cv.h[5] = __float2bfloat16(v1.y * LOG2E);
        cv.h[6] = __float2bfloat16(v1.z * LOG2E);
        cv.h[7] = __float2bfloat16(v1.w * LOG2E);
        *reinterpret_cast<uint4*>(tb + (size_t)row * D + e * 8) = cv.u;
    } else {
        const int row = (blockIdx.x - M / 32) * 32 + (tid >> 3);
        const float4* p = reinterpret_cast<const float4*>(trainX + (size_t)row * D + e * 8);
        float4 v0 = p[0], v1 = p[1];
        float r2 = v0.x * v0.x + v0.y * v0.y + v0.z * v0.z + v0.w * v0.w
                 + v1.x * v1.x + v1.y * v1.y + v1.z * v1.z + v1.w * v1.w;
        r2 += __shfl_xor(r2, 1, 64);
        r2 += __shfl_xor(r2, 2, 64);
        r2 += __shfl_xor(r2, 4, 64);
        if (e == 0) lw2[row] = __builtin_amdgcn_logf(sw[row]) - HL2E * r2 + B0;
        union { __hip_bfloat16 h[8]; uint4 u; } cv;
        cv.h[0] = __float2bfloat16(v0.x);
        cv.h[1] = __float2bfloat16(v0.y);
        cv.h[2] = __float2bfloat16(v0.z);
        cv.h[3] = __float2bfloat16(v0.w);
        cv.h[4] = __float2bfloat16(v1.x);
        cv.h[5] = __float2bfloat16(v1.y);
        cv.h[6] = __float2bfloat16(v1.z);
        cv.h[7] = __float2bfloat16(v1.w);
        *reinterpret_cast<uint4*>(rb + (size_t)row * D + e * 8) = cv.u;
    }
}

// Direct global->LDS DMA, 16 B/lane (no VGPR round-trip => nothing to spill).
__device__ __forceinline__ void dma16(const void* g, void* l) {
    __builtin_amdgcn_global_load_lds(
        (const __attribute__((address_space(1))) unsigned int*)g,
        (__attribute__((address_space(3))) unsigned int*)l, 16, 0, 0);
}

// Stage one 64x64 bf16 B-tile (8 KB): wave w issues 2 DMAs; call g covers
// rows g*8..g*8+7: lane L fetches row g*8+(L&7), k-chunk (L>>3), landing at
// base+g*1024+L*16 => LDS(rr,kc) = (rr>>3)*1024 + kc*128 + (rr&7)*16.
__device__ __forceinline__ void dma_tile(const __hip_bfloat16* tr, int nt,
                                         char* Bsb, int w, int lane) {
#pragma unroll
    for (int i = 0; i < 2; ++i) {
        const int g = w * 2 + i;
        const __hip_bfloat16* gp =
            tr + (size_t)(nt + g * 8 + (lane & 7)) * D + (lane >> 3) * 8;
        dma16(gp, Bsb + g * 1024);
    }
}

// Compute one 512(rows) x 64(cols) tile from LDS. Each wave owns FOUR
// row-groups (128 rows): every B-fragment ds_read feeds FOUR MFMAs,
// cutting the per-CU LDS pipe (the dominant throughput floor, 10.2 us in
// the 1-rg layout) by 4x. rg chains are written sequentially (one acc
// live textually); the 256-VGPR cap gives the scheduler room to pipeline
// 2-3 chains without spilling (rounds 2/3 failed on 64/84-reg caps, not
// on the idea). Schraudolph exp2 (no trans pipe) + zacc C-operand reuse.
__device__ __forceinline__ void compute_tile(const char* Bs, float lwa, float lwb,
                                             const v8bf af[4][4], const v16f& zacc,
                                             float srun[4][16], int c, int h) {
#pragma unroll
    for (int s = 0; s < 2; ++s) {
        const float cs = fmaf(s ? lwb : lwa, SCH_K, SCH_C);
        v8bf bf[4];
#pragma unroll
        for (int t = 0; t < 4; ++t)
            bf[t] = *reinterpret_cast<const v8bf*>(
                Bs + (s * 4 + (c >> 3)) * 1024 + (2 * t + h) * 128 + (c & 7) * 16);
#pragma unroll
        for (int rg = 0; rg < 4; ++rg) {
            v16f acc = __builtin_amdgcn_mfma_f32_32x32x16_bf16(af[rg][0], bf[0], zacc, 0, 0, 0);
#pragma unroll
            for (int t = 1; t < 4; ++t)
                acc = __builtin_amdgcn_mfma_f32_32x32x16_bf16(af[rg][t], bf[t], acc, 0, 0, 0);
#pragma unroll
            for (int r = 0; r < 16; ++r) {
                float tv = fmaf(acc[r], SCH_K, cs);
                tv = fmaxf(tv, 0.0f);
                srun[rg][r] += __int_as_float((int)tv);
            }
        }
    }
}

// Main: 512 test rows x 512 train cols per block, 256 threads (4 waves),
// each wave owns 128 rows (4 row-groups). Grid = 16*32 = 512 = exactly
// 2/CU, single round. LDS-read redundancy drops 4x (1 ds_read -> 4 MFMA);
// (256,2) caps VGPR at 256 so the ~190-reg demand CANNOT spill (the
// round-2/3 failure mode is excluded by construction). Occupancy 2
// blocks/CU (2 waves/SIMD) is covered by 4 independent MFMA chains of
// per-wave ILP + cross-block barrier de-phasing. LDS 67.6 KB (dbuf 16 KB;
// 512x33 f32 red reuses) x 2 = 135 KB/CU.
__global__ __launch_bounds__(256, 2) void gk_main(const __hip_bfloat16* __restrict__ ta,
                                                  const __hip_bfloat16* __restrict__ tr,
                                                  const float* __restrict__ lw2,
                                                  float* __restrict__ part) {
    __shared__ __align__(16) char smem[67584];   // dbuf 2x8K; red 512x33 f32 reuses
    const int tid = threadIdx.x;
    const int w = tid >> 6;          // 0..3
    const int lane = tid & 63;
    const int c = lane & 31;
    const int h = lane >> 5;

    // XCD swizzle: xcd = bid&7 owns chunks 4x..4x+3 (2048 train rows L2-local)
    const int bid = blockIdx.x;
    const int xcd = bid & 7;
    const int j = bid >> 3;                 // 0..63
    const int chunk = xcd * 4 + (j & 3);    // 0..31
    const int m0 = (j >> 2) * 512;          // 16 m-tiles
    const int n0 = chunk * NCHK;

    char* const Bs0 = smem;
    char* const Bs1 = smem + 8192;

    // kick off tile 0 DMA + tile 0 bias loads, then A fragments while they fly
    dma_tile(tr, n0, Bs0, w, lane);
    float lwa0 = lw2[n0 + c], lwb0 = lw2[n0 + 32 + c];

    // A fragments: wave w, row-group rg covers rows m0 + rg*128 + w*32 .. +31
    v8bf af[4][4];
#pragma unroll
    for (int rg = 0; rg < 4; ++rg) {
        const __hip_bfloat16* arow = ta + (size_t)(m0 + rg * 128 + w * 32 + c) * D;
#pragma unroll
        for (int t = 0; t < 4; ++t)
            af[rg][t] = *reinterpret_cast<const v8bf*>(arow + (2 * t + h) * 8);
    }

    v16f zacc;
#pragma unroll
    for (int r = 0; r < 16; ++r) zacc[r] = 0.f;
    float srun[4][16];
#pragma unroll
    for (int rg = 0; rg < 4; ++rg)
#pragma unroll
        for (int r = 0; r < 16; ++r) srun[rg][r] = 0.f;

    __syncthreads();                                   // tile0 staged

    // 8 tiles, ping-pong Bs0/Bs1; fully unrolled so all offsets are static.
#pragma unroll
    for (int s8 = 0; s8 < 4; ++s8) {
        const int t0 = s8 * 2;
        // odd tile t0+1 -> Bs1
        dma_tile(tr, n0 + (t0 + 1) * 64, Bs1, w, lane);
        const float lwa1 = lw2[n0 + (t0 + 1) * 64 + c];
        const float lwb1 = lw2[n0 + (t0 + 1) * 64 + 32 + c];
        compute_tile(Bs0, lwa0, lwb0, af, zacc, srun, c, h);
        __syncthreads();                               // tile t0+1 staged
        if (t0 + 2 < 8) {
            // even tile t0+2 -> Bs0
            dma_tile(tr, n0 + (t0 + 2) * 64, Bs0, w, lane);
            lwa0 = lw2[n0 + (t0 + 2) * 64 + c];
            lwb0 = lw2[n0 + (t0 + 2) * 64 + 32 + c];
        }
        compute_tile(Bs1, lwa1, lwb1, af, zacc, srun, c, h);
        __syncthreads();                               // tile t0+2 staged / drain
    }

    // ---- cross-lane row sum (cols live across 32 lanes) ----
    // last loop barrier already separates compute from smem reuse
    float* red = reinterpret_cast<float*>(smem);   // 512 x 33 f32 (67584 B)
#pragma unroll
    for (int rg = 0; rg < 4; ++rg)
#pragma unroll
        for (int r = 0; r < 16; ++r) {
            int rowl = (r & 3) + 8 * (r >> 2) + 4 * h;
            red[(rg * 128 + w * 32 + rowl) * 33 + c] = srun[rg][r];
        }
    __syncthreads();
#pragma unroll
    for (int rr = 0; rr < 2; ++rr) {
        const int row = rr * 256 + tid;
        float G = 0.f;
#pragma unroll
        for (int c2 = 0; c2 < 32; ++c2) G += red[row * 33 + c2];
        part[(size_t)chunk * M + m0 + row] = G;   // [chunk][m] coalesced
    }
}

__global__ __launch_bounds__(256) void gk_merge(const float* __restrict__ part,
                                                const float* __restrict__ au2,
                                                const float* __restrict__ sw,
                                                float* __restrict__ out) {
    __shared__ float red[256];
    const int tid = threadIdx.x;
    // W = sum(sw), recomputed per block (64 KB, L2-resident, fully parallel)
    float s = 0.f;
    const float4* p4 = reinterpret_cast<const float4*>(sw);
    for (int i = tid; i < N / 4; i += 256) {
        float4 v = p4[i];
        s += v.x + v.y + v.z + v.w;
    }
    red[tid] = s;
    __syncthreads();
    for (int off = 128; off > 0; off >>= 1) {
        if (tid < off) red[tid] += red[tid + off];
        __syncthreads();
    }
    const float W = red[0];

    const int r = blockIdx.x * 256 + tid;
    float G = 0.f;
#pragma unroll
    for (int p = 0; p < PCH; ++p) G += part[(size_t)p * M + r];
    out[r] = LN2 * (au2[r] + __builtin_amdgcn_logf(fmaxf(G, 1e-30f)) - B0
                   - __builtin_amdgcn_logf(W)) - ZC;
}

extern "C" void kernel_launch(void* const* d_in, const int* in_sizes, int n_in,
                              void* d_out, int out_size, void* d_ws, size_t ws_size,
                              hipStream_t stream) {
    const float* testX  = (const float*)d_in[0];   // [8192, 64]
    const float* trainX = (const float*)d_in[1];   // [16384, 64]
    const float* sw     = (const float*)d_in[2];   // [16384]
    float* out = (float*)d_out;                    // [8192]
    char* wsb = (char*)d_ws;

    float* au2  = (float*)(wsb + B_AU2);
    float* lw2  = (float*)(wsb + B_LW2);
    float* part = (float*)(wsb + B_PART);
    __hip_bfloat16* tb = (__hip_bfloat16*)(wsb + B_TB);
    __hip_bfloat16* rb = (__hip_bfloat16*)(wsb + B_TR);

    gk_prep<<<M / 32 + N / 32, 256, 0, stream>>>(testX, trainX, sw, tb, rb, au2, lw2);
    gk_main<<<(M / 512) * PCH, 256, 0, stream>>>(tb, rb, lw2, part);
    gk_merge<<<M / 256, 256, 0, stream>>>(part, au2, sw, out);
}

// Round 10
// 92.501 us; speedup vs baseline: 5.9077x; 5.9077x over previous
//
#include <hip/hip_runtime.h>
#include <hip/hip_bf16.h>
#include <math.h>

// ---------------- problem constants ----------------
#define M 8192
#define N 16384
#define D 64
#define ZC 58.81206612509905f        // 32*log(2*pi), h=1
#define B0 24.0f                     // exp2-domain bias (headroom; u<=0)
#define LOG2E 1.4426950408889634f
#define HL2E 0.7213475204444817f     // 0.5*log2(e)
#define LN2 0.6931471805599453f

// Schraudolph exp2: 2^u ~= bitcast(int(u*2^23 + (127 - 0.0435)*2^23)).
// Bias-corrected midpoint => max rel err ~±3% (log-output err <= 0.04,
// same order as existing bf16 dot noise; tolerance 0.5).
#define SCH_K 8388608.0f             // 2^23
#define SCH_C (1065353216.0f - 0.0435f * 8388608.0f)

#define PCH 16
#define NCHK (N / PCH)               // 1024 train cols per block

typedef short v8bf __attribute__((ext_vector_type(8)));   // 8 bf16 (4 VGPRs)
typedef float v16f __attribute__((ext_vector_type(16)));

// ws layout (bytes)
#define B_AU2  0                        // 8192 f32  (32 KB)
#define B_LW2  32768                    // 16384 f32 (64 KB)
#define B_PART 98304                    // 16*8192 f32 (512 KB), [chunk][m]
#define B_TB   622592                   // 8192*64 bf16 (1 MB)
#define B_TR   1671168                  // 16384*64 bf16 (2 MB)

// Fused prep: blocks 0..255 convert testX -> bf16(log2e*x) + au2;
// blocks 256..767 convert trainX -> bf16 + lw2 = log2(w) - hl2e*r2 + B0.
__global__ __launch_bounds__(256) void gk_prep(const float* __restrict__ testX,
                                               const float* __restrict__ trainX,
                                               const float* __restrict__ sw,
                                               __hip_bfloat16* __restrict__ tb,
                                               __hip_bfloat16* __restrict__ rb,
                                               float* __restrict__ au2,
                                               float* __restrict__ lw2) {
    const int tid = threadIdx.x;
    const int e = tid & 7;
    if (blockIdx.x < M / 32) {
        const int row = blockIdx.x * 32 + (tid >> 3);
        const float4* p = reinterpret_cast<const float4*>(testX + (size_t)row * D + e * 8);
        float4 v0 = p[0], v1 = p[1];
        float t2 = v0.x * v0.x + v0.y * v0.y + v0.z * v0.z + v0.w * v0.w
                 + v1.x * v1.x + v1.y * v1.y + v1.z * v1.z + v1.w * v1.w;
        t2 += __shfl_xor(t2, 1, 64);
        t2 += __shfl_xor(t2, 2, 64);
        t2 += __shfl_xor(t2, 4, 64);
        if (e == 0) au2[row] = -HL2E * t2;
        union { __hip_bfloat16 h[8]; uint4 u; } cv;
        cv.h[0] = __float2bfloat16(v0.x * LOG2E);
        cv.h[1] = __float2bfloat16(v0.y * LOG2E);
        cv.h[2] = __float2bfloat16(v0.z * LOG2E);
        cv.h[3] = __float2bfloat16(v0.w * LOG2E);
        cv.h[4] = __float2bfloat16(v1.x * LOG2E);
        cv.h[5] = __float2bfloat16(v1.y * LOG2E);
        cv.h[6] = __float2bfloat16(v1.z * LOG2E);
        cv.h[7] = __float2bfloat16(v1.w * LOG2E);
        *reinterpret_cast<uint4*>(tb + (size_t)row * D + e * 8) = cv.u;
    } else {
        const int row = (blockIdx.x - M / 32) * 32 + (tid >> 3);
        const float4* p = reinterpret_cast<const float4*>(trainX + (size_t)row * D + e * 8);
        float4 v0 = p[0], v1 = p[1];
        float r2 = v0.x * v0.x + v0.y * v0.y + v0.z * v0.z + v0.w * v0.w
                 + v1.x * v1.x + v1.y * v1.y + v1.z * v1.z + v1.w * v1.w;
        r2 += __shfl_xor(r2, 1, 64);
        r2 += __shfl_xor(r2, 2, 64);
        r2 += __shfl_xor(r2, 4, 64);
        if (e == 0) lw2[row] = __builtin_amdgcn_logf(sw[row]) - HL2E * r2 + B0;
        union { __hip_bfloat16 h[8]; uint4 u; } cv;
        cv.h[0] = __float2bfloat16(v0.x);
        cv.h[1] = __float2bfloat16(v0.y);
        cv.h[2] = __float2bfloat16(v0.z);
        cv.h[3] = __float2bfloat16(v0.w);
        cv.h[4] = __float2bfloat16(v1.x);
        cv.h[5] = __float2bfloat16(v1.y);
        cv.h[6] = __float2bfloat16(v1.z);
        cv.h[7] = __float2bfloat16(v1.w);
        *reinterpret_cast<uint4*>(rb + (size_t)row * D + e * 8) = cv.u;
    }
}

// Direct global->LDS DMA, 16 B/lane (no VGPR round-trip => nothing to spill).
__device__ __forceinline__ void dma16(const void* g, void* l) {
    __builtin_amdgcn_global_load_lds(
        (const __attribute__((address_space(1))) unsigned int*)g,
        (__attribute__((address_space(3))) unsigned int*)l, 16, 0, 0);
}

// Stage one 64x64 bf16 B-tile (8 KB): wave w issues 2 DMAs; call g covers
// rows g*8..g*8+7: lane L fetches row g*8+(L&7), k-chunk (L>>3), landing at
// base+g*1024+L*16 => LDS(rr,kc) = (rr>>3)*1024 + kc*128 + (rr&7)*16.
__device__ __forceinline__ void dma_tile(const __hip_bfloat16* tr, int nt,
                                         char* Bsb, int w, int lane) {
#pragma unroll
    for (int i = 0; i < 2; ++i) {
        const int g = w * 2 + i;
        const __hip_bfloat16* gp =
            tr + (size_t)(nt + g * 8 + (lane & 7)) * D + (lane >> 3) * 8;
        dma16(gp, Bsb + g * 1024);
    }
}

// Compute one 128(rows) x 64(cols) tile from LDS. Dual independent
// accumulators (accA/accB) de-phase the two col-subtiles: subtile-B's MFMA
// chain no longer waits for subtile-A's 130-op Schraudolph tail (the WAR
// hazard of the single-acc form). Addressing is bit-identical to the
// proven round-5 layout. Arch-reg ledger: af16+bf16+srun16+addr~14 ~= 62;
// AGPR side: accA+accB+zacc = 48 (both under the 64/64 split of the
// (256,4) 128-reg cap -> spill-impossible).
__device__ __forceinline__ void compute_tile(const char* Bs, float lwa, float lwb,
                                             const v8bf af[4], const v16f& zacc,
                                             float srun[16], int c, int h) {
    const int base = (c >> 3) * 1024 + h * 128 + (c & 7) * 16;
    v8bf bf[4];
    // ---- subtile A (cols 0..31): batched reads, dependent MFMA chain
#pragma unroll
    for (int t = 0; t < 4; ++t)
        bf[t] = *reinterpret_cast<const v8bf*>(Bs + base + t * 256);
    v16f accA = __builtin_amdgcn_mfma_f32_32x32x16_bf16(af[0], bf[0], zacc, 0, 0, 0);
#pragma unroll
    for (int t = 1; t < 4; ++t)
        accA = __builtin_amdgcn_mfma_f32_32x32x16_bf16(af[t], bf[t], accA, 0, 0, 0);
    // ---- subtile B (cols 32..63)
#pragma unroll
    for (int t = 0; t < 4; ++t)
        bf[t] = *reinterpret_cast<const v8bf*>(Bs + 4096 + base + t * 256);
    v16f accB = __builtin_amdgcn_mfma_f32_32x32x16_bf16(af[0], bf[0], zacc, 0, 0, 0);
#pragma unroll
    for (int t = 1; t < 4; ++t)
        accB = __builtin_amdgcn_mfma_f32_32x32x16_bf16(af[t], bf[t], accB, 0, 0, 0);
    // ---- tails: A's tail is independent of chain-B -> scheduler overlaps
    const float csa = fmaf(lwa, SCH_K, SCH_C);
    const float csb = fmaf(lwb, SCH_K, SCH_C);
#pragma unroll
    for (int r = 0; r < 16; ++r) {
        float tv = fmaf(accA[r], SCH_K, csa);
        tv = fmaxf(tv, 0.0f);
        srun[r] += __int_as_float((int)tv);
    }
#pragma unroll
    for (int r = 0; r < 16; ++r) {
        float tv = fmaf(accB[r], SCH_K, csb);
        tv = fmaxf(tv, 0.0f);
        srun[r] += __int_as_float((int)tv);
    }
}

// Main: 128 test rows x 1024 train cols per block, 256 threads (4 waves),
// round-5 skeleton: triple-buffered LDS + counted vmcnt. Grid = 64*16 =
// 1024 = exactly 4/CU, single round. Per tile, 4 vmem ops/wave
// (2 global_load_lds + 2 lw2 bias loads); vmcnt(4) before the barrier
// keeps tile t+1's ops in flight across it; vmcnt(0) only at the last
// tile. ROUND-9 RACE FIX: sched_barrier(0) immediately after s_barrier —
// the raw s_barrier intrinsic is NOT a compiler memory fence, and round-9's
// batched ds_reads were hoisted above it, reading rows whose DMA (issued
// by OTHER waves, not covered by my vmcnt) hadn't landed. The fence pins
// all ds_reads below the barrier at zero runtime cost.
__global__ __launch_bounds__(256, 4) void gk_main(const __hip_bfloat16* __restrict__ ta,
                                                  const __hip_bfloat16* __restrict__ tr,
                                                  const float* __restrict__ lw2,
                                                  float* __restrict__ part) {
    __shared__ __align__(16) char smem[24576];   // 3 x 8 KB tiles; red 128x33 f32 reuses
    const int tid = threadIdx.x;
    const int w = tid >> 6;
    const int lane = tid & 63;
    const int c = lane & 31;
    const int h = lane >> 5;

    // XCD swizzle: xcd = bid&7 owns chunks 2x..2x+1 (2048 train rows L2-local)
    const int bid = blockIdx.x;
    const int xcd = bid & 7;
    const int j = bid >> 3;                 // 0..127
    const int chunk = xcd * 2 + (j & 1);    // 0..15
    const int m0 = (j >> 1) * 128;          // 64 m-tiles
    const int n0 = chunk * NCHK;

    char* const Bs[3] = { smem, smem + 8192, smem + 16384 };

    float lwa[3], lwb[3];

    // prologue: tile 0 DMA + bias, then A fragments, then tile 1 DMA + bias.
    dma_tile(tr, n0, Bs[0], w, lane);
    lwa[0] = lw2[n0 + c]; lwb[0] = lw2[n0 + 32 + c];

    const __hip_bfloat16* arow = ta + (size_t)(m0 + w * 32 + c) * D;
    v8bf af[4];
#pragma unroll
    for (int t = 0; t < 4; ++t)
        af[t] = *reinterpret_cast<const v8bf*>(arow + (2 * t + h) * 8);

    dma_tile(tr, n0 + 64, Bs[1], w, lane);
    lwa[1] = lw2[n0 + 64 + c]; lwb[1] = lw2[n0 + 96 + c];

    v16f zacc;
#pragma unroll
    for (int r = 0; r < 16; ++r) zacc[r] = 0.f;
    float srun[16];
#pragma unroll
    for (int r = 0; r < 16; ++r) srun[r] = 0.f;

    // main loop: 16 tiles, fully unrolled (static %3 indices).
#pragma unroll
    for (int t = 0; t < 16; ++t) {
        if (t < 15) {
            asm volatile("s_waitcnt vmcnt(4)" ::: "memory");   // tile t landed; t+1 in flight
        } else {
            asm volatile("s_waitcnt vmcnt(0)" ::: "memory");   // last tile: full drain
        }
        __builtin_amdgcn_s_barrier();                          // all waves' tile-t data visible
        __builtin_amdgcn_sched_barrier(0);                     // pin ds_reads below barrier
        if (t + 2 < 16) {
            dma_tile(tr, n0 + (t + 2) * 64, Bs[(t + 2) % 3], w, lane);
            lwa[(t + 2) % 3] = lw2[n0 + (t + 2) * 64 + c];
            lwb[(t + 2) % 3] = lw2[n0 + (t + 2) * 64 + 32 + c];
        }
        compute_tile(Bs[t % 3], lwa[t % 3], lwb[t % 3], af, zacc, srun, c, h);
    }

    // ---- cross-lane row sum (cols live across 32 lanes) ----
    __syncthreads();                               // compute done; reuse smem
    float* red = reinterpret_cast<float*>(smem);   // 128 x 33 f32 (16896 B)
#pragma unroll
    for (int r = 0; r < 16; ++r) {
        int rowl = (r & 3) + 8 * (r >> 2) + 4 * h;
        red[(w * 32 + rowl) * 33 + c] = srun[r];
    }
    __syncthreads();
    if (tid < 128) {
        float G = 0.f;
#pragma unroll
        for (int c2 = 0; c2 < 32; ++c2) G += red[tid * 33 + c2];
        part[(size_t)chunk * M + m0 + tid] = G;   // [chunk][m] coalesced
    }
}

__global__ __launch_bounds__(256) void gk_merge(const float* __restrict__ part,
                                                const float* __restrict__ au2,
                                                const float* __restrict__ sw,
                                                float* __restrict__ out) {
    __shared__ float red[256];
    const int tid = threadIdx.x;
    // W = sum(sw), recomputed per block (64 KB, L2-resident, fully parallel)
    float s = 0.f;
    const float4* p4 = reinterpret_cast<const float4*>(sw);
    for (int i = tid; i < N / 4; i += 256) {
        float4 v = p4[i];
        s += v.x + v.y + v.z + v.w;
    }
    red[tid] = s;
    __syncthreads();
    for (int off = 128; off > 0; off >>= 1) {
        if (tid < off) red[tid] += red[tid + off];
        __syncthreads();
    }
    const float W = red[0];

    const int r = blockIdx.x * 256 + tid;
    float G = 0.f;
#pragma unroll
    for (int p = 0; p < PCH; ++p) G += part[(size_t)p * M + r];
    out[r] = LN2 * (au2[r] + __builtin_amdgcn_logf(fmaxf(G, 1e-30f)) - B0
                   - __builtin_amdgcn_logf(W)) - ZC;
}

extern "C" void kernel_launch(void* const* d_in, const int* in_sizes, int n_in,
                              void* d_out, int out_size, void* d_ws, size_t ws_size,
                              hipStream_t stream) {
    const float* testX  = (const float*)d_in[0];   // [8192, 64]
    const float* trainX = (const float*)d_in[1];   // [16384, 64]
    const float* sw     = (const float*)d_in[2];   // [16384]
    float* out = (float*)d_out;                    // [8192]
    char* wsb = (char*)d_ws;

    float* au2  = (float*)(wsb + B_AU2);
    float* lw2  = (float*)(wsb + B_LW2);
    float* part = (float*)(wsb + B_PART);
    __hip_bfloat16* tb = (__hip_bfloat16*)(wsb + B_TB);
    __hip_bfloat16* rb = (__hip_bfloat16*)(wsb + B_TR);

    gk_prep<<<M / 32 + N / 32, 256, 0, stream>>>(testX, trainX, sw, tb, rb, au2, lw2);
    gk_main<<<(M / 128) * PCH, 256, 0, stream>>>(tb, rb, lw2, part);
    gk_merge<<<M / 256, 256, 0, stream>>>(part, au2, sw, out);
}